// Round 1
// baseline (2564.295 us; speedup 1.0000x reference)
//
#include <hip/hip_runtime.h>
#include <hip/hip_bf16.h>
#include <math.h>

// ---------------------------------------------------------------------------
// Fused linear cross-entropy:  hidden(2047x2048) @ W^T(151936x2048) -> LSE - tgt
// Round 1: bf16-convert pass + m97-style 128x128 MFMA GEMM with online-LSE
// epilogue + per-row reduction. Exact-fp32 target dot in the reduction kernel.
// ---------------------------------------------------------------------------

#define V_SIZE   151936
#define H_SIZE   2048
#define M_ROWS   2048      // 2047 real rows + 1 zero pad row
#define M_REAL   2047
#define NB_CNT   1187      // 151936 / 128
#define BM 128
#define BN 128
#define BK 64
#define IGNORE_INDEX (-100)

typedef short bf16x8 __attribute__((ext_vector_type(8)));
typedef float floatx4 __attribute__((ext_vector_type(4)));

__device__ __forceinline__ unsigned short f2bf_rne(float f) {
    union { float f; unsigned u; } x; x.f = f;
    unsigned r = (x.u + 0x7fffu + ((x.u >> 16) & 1u)) >> 16;
    return (unsigned short)r;
}

__device__ __forceinline__ void gload16(const void* g, void* l) {
    __builtin_amdgcn_global_load_lds(
        (const __attribute__((address_space(1))) unsigned int*)g,
        (__attribute__((address_space(3))) unsigned int*)l, 16, 0, 0);
}

// ---- conversion kernels ----------------------------------------------------

__global__ void cvt_weight(const float4* __restrict__ in,
                           ushort4* __restrict__ out, long n4) {
    long i = (long)blockIdx.x * blockDim.x + threadIdx.x;
    long stride = (long)gridDim.x * blockDim.x;
    for (; i < n4; i += stride) {
        float4 v = in[i];
        ushort4 o;
        o.x = f2bf_rne(v.x); o.y = f2bf_rne(v.y);
        o.z = f2bf_rne(v.z); o.w = f2bf_rne(v.w);
        out[i] = o;
    }
}

__global__ void cvt_hidden(const float4* __restrict__ in,
                           ushort4* __restrict__ out) {
    const long n4 = (long)M_ROWS * H_SIZE / 4;       // 1,048,576
    const long valid4 = (long)M_REAL * H_SIZE / 4;   // 1,048,064
    long i = (long)blockIdx.x * blockDim.x + threadIdx.x;
    long stride = (long)gridDim.x * blockDim.x;
    for (; i < n4; i += stride) {
        ushort4 o;
        if (i < valid4) {
            float4 v = in[i];
            o.x = f2bf_rne(v.x); o.y = f2bf_rne(v.y);
            o.z = f2bf_rne(v.z); o.w = f2bf_rne(v.w);
        } else {
            o.x = 0; o.y = 0; o.z = 0; o.w = 0;
        }
        out[i] = o;
    }
}

// ---- main GEMM + per-tile online-LSE epilogue ------------------------------
// grid = (16 m-blocks fast, 1187 n-blocks), block = 256 threads (4 waves 2x2)

__global__ __launch_bounds__(256) void gemm_lse(
    const unsigned short* __restrict__ hbf,   // [2048][2048] bf16 bits
    const unsigned short* __restrict__ wbf,   // [151936][2048] bf16 bits
    float* __restrict__ pmax,                 // [1187][2048]
    float* __restrict__ psum) {               // [1187][2048]
    __shared__ short ldsA[BM * BK];   // [128][64] row-major (m, k)
    __shared__ short ldsB[BN * BK];   // [128][64] row-major (n, k)
    __shared__ float eM[BM][2];
    __shared__ float eS[BM][2];

    const int t    = threadIdx.x;
    const int lane = t & 63;
    const int w    = t >> 6;
    const int wm   = w >> 1;          // wave row (0..1) -> 64 rows
    const int wn   = w & 1;           // wave col (0..1) -> 64 cols
    const int mb   = blockIdx.x;
    const int nb   = blockIdx.y;
    const int m0   = mb * BM;
    const int n0   = nb * BN;

    // staging source pointers: thread t loads 16B = 8 bf16 of row (t>>3),
    // k-offset (t&7)*8; issue i adds 32 rows.
    const unsigned short* pa = hbf + (size_t)(m0 + (t >> 3)) * H_SIZE + (t & 7) * 8;
    const unsigned short* pb = wbf + (size_t)(n0 + (t >> 3)) * H_SIZE + (t & 7) * 8;
    short* la = &ldsA[t * 8];   // byte off = t*16
    short* lb = &ldsB[t * 8];

    floatx4 zero4 = {0.f, 0.f, 0.f, 0.f};
    floatx4 acc[4][4];
#pragma unroll
    for (int i = 0; i < 4; ++i)
#pragma unroll
        for (int j = 0; j < 4; ++j) acc[i][j] = zero4;

    const int fr = lane & 15;       // fragment row/col
    const int fq = lane >> 4;       // k-block selector (0..3)

    for (int kt = 0; kt < H_SIZE / BK; ++kt) {
        const int kof = kt * BK;
#pragma unroll
        for (int i = 0; i < 4; ++i) {
            gload16(pa + (size_t)i * 32 * H_SIZE + kof, la + i * 2048);
            gload16(pb + (size_t)i * 32 * H_SIZE + kof, lb + i * 2048);
        }
        __syncthreads();
#pragma unroll
        for (int kk = 0; kk < 2; ++kk) {
            bf16x8 af[4], bfv[4];
#pragma unroll
            for (int i = 0; i < 4; ++i)
                af[i] = *(const bf16x8*)&ldsA[(wm * 64 + i * 16 + fr) * BK + kk * 32 + fq * 8];
#pragma unroll
            for (int j = 0; j < 4; ++j)
                bfv[j] = *(const bf16x8*)&ldsB[(wn * 64 + j * 16 + fr) * BK + kk * 32 + fq * 8];
#pragma unroll
            for (int i = 0; i < 4; ++i)
#pragma unroll
                for (int j = 0; j < 4; ++j)
                    acc[i][j] = __builtin_amdgcn_mfma_f32_16x16x32_bf16(
                        af[i], bfv[j], acc[i][j], 0, 0, 0);
        }
        __syncthreads();
    }

    // epilogue: per-row max + sum(exp) over this block's 128 vocab columns.
    // C/D layout: col = lane&15, row = (lane>>4)*4 + reg.
#pragma unroll
    for (int i = 0; i < 4; ++i) {
#pragma unroll
        for (int r = 0; r < 4; ++r) {
            float v = -INFINITY;
#pragma unroll
            for (int j = 0; j < 4; ++j) v = fmaxf(v, acc[i][j][r]);
            for (int off = 1; off < 16; off <<= 1)
                v = fmaxf(v, __shfl_xor(v, off, 64));
            float s = 0.f;
#pragma unroll
            for (int j = 0; j < 4; ++j) s += expf(acc[i][j][r] - v);
            for (int off = 1; off < 16; off <<= 1)
                s += __shfl_xor(s, off, 64);
            if (fr == 0) {
                int row = wm * 64 + i * 16 + fq * 4 + r;
                eM[row][wn] = v;
                eS[row][wn] = s;
            }
        }
    }
    __syncthreads();
    if (t < BM) {
        float ma = eM[t][0], mb2 = eM[t][1];
        float Mx = fmaxf(ma, mb2);
        float Sx = eS[t][0] * expf(ma - Mx) + eS[t][1] * expf(mb2 - Mx);
        size_t grow = (size_t)m0 + t;
        pmax[(size_t)nb * M_ROWS + grow] = Mx;
        psum[(size_t)nb * M_ROWS + grow] = Sx;
    }
}

// ---- per-row reduction: combine partials + exact fp32 target dot -----------

__global__ void zero_acc(float* a) {
    if (threadIdx.x < 2) a[threadIdx.x] = 0.f;
}

__global__ __launch_bounds__(256) void reduce_rows(
    const float* __restrict__ hid,      // original fp32 hidden (row m = shift row m)
    const int* __restrict__ labels,     // int32 labels, length 2048
    const float* __restrict__ wt,       // fp32 weight
    const float* __restrict__ pmax,
    const float* __restrict__ psum,
    float* __restrict__ accum) {
    const int m = blockIdx.x;           // 0..2046
    const int t = threadIdx.x;
    const int lbl = labels[m + 1];
    const bool valid = (lbl != IGNORE_INDEX);

    float dot = 0.f;
    if (valid) {
        int li = lbl < 0 ? 0 : lbl;
        const float4* hr = (const float4*)(hid + (size_t)m * H_SIZE);
        const float4* wr = (const float4*)(wt + (size_t)li * H_SIZE);
#pragma unroll
        for (int i = 0; i < 2; ++i) {
            float4 a = hr[t + i * 256];
            float4 b = wr[t + i * 256];
            dot += a.x * b.x + a.y * b.y + a.z * b.z + a.w * b.w;
        }
    }

    float M = -INFINITY, S = 0.f;
    for (int nbi = t; nbi < NB_CNT; nbi += 256) {
        float m2 = pmax[(size_t)nbi * M_ROWS + m];
        float s2 = psum[(size_t)nbi * M_ROWS + m];
        if (m2 > M) { S = S * expf(M - m2) + s2; M = m2; }
        else        { S += s2 * expf(m2 - M); }
    }
    // butterfly over 64-lane wave
    for (int off = 1; off < 64; off <<= 1) {
        float M2 = __shfl_xor(M, off, 64);
        float S2 = __shfl_xor(S, off, 64);
        float nm = fmaxf(M, M2);
        S = S * expf(M - nm) + S2 * expf(M2 - nm);
        M = nm;
        dot += __shfl_xor(dot, off, 64);
    }
    __shared__ float rM[4], rS[4], rD[4];
    const int wv = t >> 6, lane = t & 63;
    if (lane == 0) { rM[wv] = M; rS[wv] = S; rD[wv] = dot; }
    __syncthreads();
    if (t == 0) {
        float Mx = rM[0], Sx = rS[0], D = rD[0];
        for (int i = 1; i < 4; ++i) {
            float nm = fmaxf(Mx, rM[i]);
            Sx = Sx * expf(Mx - nm) + rS[i] * expf(rM[i] - nm);
            Mx = nm;
            D += rD[i];
        }
        if (valid) {
            atomicAdd(&accum[0], (Mx + logf(Sx)) - D);
            atomicAdd(&accum[1], 1.0f);
        }
    }
}

__global__ void finalize(const float* __restrict__ accum, float* __restrict__ out) {
    out[0] = accum[0] / accum[1];
}

__global__ void sentinel(float* out) { out[0] = -12345.0f; }

// ---------------------------------------------------------------------------

extern "C" void kernel_launch(void* const* d_in, const int* in_sizes, int n_in,
                              void* d_out, int out_size, void* d_ws, size_t ws_size,
                              hipStream_t stream) {
    const float* hid    = (const float*)d_in[0];
    const int*   labels = (const int*)d_in[1];
    const float* wt     = (const float*)d_in[2];
    float* out = (float*)d_out;

    const size_t wbf_bytes  = (size_t)V_SIZE * H_SIZE * 2;     // 622,333,952
    const size_t hbf_bytes  = (size_t)M_ROWS * H_SIZE * 2;     //   8,388,608
    const size_t part_bytes = (size_t)NB_CNT * M_ROWS * 4;     //   9,723,904
    const size_t off_wbf  = 0;
    const size_t off_hbf  = off_wbf + wbf_bytes;
    const size_t off_pmax = off_hbf + hbf_bytes;
    const size_t off_psum = off_pmax + part_bytes;
    const size_t off_acc  = off_psum + part_bytes;
    const size_t need     = off_acc + 16;

    if (ws_size < need) {   // diagnosable failure: out = -12345
        sentinel<<<1, 1, 0, stream>>>(out);
        return;
    }

    unsigned short* wbf = (unsigned short*)((char*)d_ws + off_wbf);
    unsigned short* hbf = (unsigned short*)((char*)d_ws + off_hbf);
    float* pmax = (float*)((char*)d_ws + off_pmax);
    float* psum = (float*)((char*)d_ws + off_psum);
    float* accum = (float*)((char*)d_ws + off_acc);

    zero_acc<<<1, 64, 0, stream>>>(accum);

    long w4 = (long)V_SIZE * H_SIZE / 4;
    cvt_weight<<<2048, 256, 0, stream>>>((const float4*)wt, (ushort4*)wbf, w4);
    cvt_hidden<<<1024, 256, 0, stream>>>((const float4*)hid, (ushort4*)hbf);

    dim3 grid(M_ROWS / BM, NB_CNT);   // x = m-blocks (fast) for weight-slab L2 reuse
    gemm_lse<<<grid, 256, 0, stream>>>(hbf, wbf, pmax, psum);

    reduce_rows<<<M_REAL, 256, 0, stream>>>(hid, labels, wt, pmax, psum, accum);
    finalize<<<1, 1, 0, stream>>>(accum, out);
}

// Round 2
// 1783.680 us; speedup vs baseline: 1.4376x; 1.4376x over previous
//
#include <hip/hip_runtime.h>
#include <hip/hip_bf16.h>
#include <math.h>

// ---------------------------------------------------------------------------
// Fused linear cross-entropy:  hidden(2047x2048) @ W^T(151936x2048) -> LSE - tgt
// Round 2: + T2 LDS XOR-swizzle (pre-swizzled global source, linear LDS dest,
// swizzled ds_read) and XCD-aware bijective block swizzle.
// ---------------------------------------------------------------------------

#define V_SIZE   151936
#define H_SIZE   2048
#define M_ROWS   2048      // 2047 real rows + 1 zero pad row
#define M_REAL   2047
#define NB_CNT   1187      // 151936 / 128
#define BM 128
#define BN 128
#define BK 64
#define NBLK (16 * NB_CNT) // 18992, divisible by 8
#define IGNORE_INDEX (-100)

typedef short bf16x8 __attribute__((ext_vector_type(8)));
typedef float floatx4 __attribute__((ext_vector_type(4)));

__device__ __forceinline__ unsigned short f2bf_rne(float f) {
    union { float f; unsigned u; } x; x.f = f;
    unsigned r = (x.u + 0x7fffu + ((x.u >> 16) & 1u)) >> 16;
    return (unsigned short)r;
}

__device__ __forceinline__ void gload16(const void* g, void* l) {
    __builtin_amdgcn_global_load_lds(
        (const __attribute__((address_space(1))) unsigned int*)g,
        (__attribute__((address_space(3))) unsigned int*)l, 16, 0, 0);
}

// ---- conversion kernels ----------------------------------------------------

__global__ void cvt_weight(const float4* __restrict__ in,
                           ushort4* __restrict__ out, long n4) {
    long i = (long)blockIdx.x * blockDim.x + threadIdx.x;
    long stride = (long)gridDim.x * blockDim.x;
    for (; i < n4; i += stride) {
        float4 v = in[i];
        ushort4 o;
        o.x = f2bf_rne(v.x); o.y = f2bf_rne(v.y);
        o.z = f2bf_rne(v.z); o.w = f2bf_rne(v.w);
        out[i] = o;
    }
}

__global__ void cvt_hidden(const float4* __restrict__ in,
                           ushort4* __restrict__ out) {
    const long n4 = (long)M_ROWS * H_SIZE / 4;       // 1,048,576
    const long valid4 = (long)M_REAL * H_SIZE / 4;   // 1,048,064
    long i = (long)blockIdx.x * blockDim.x + threadIdx.x;
    long stride = (long)gridDim.x * blockDim.x;
    for (; i < n4; i += stride) {
        ushort4 o;
        if (i < valid4) {
            float4 v = in[i];
            o.x = f2bf_rne(v.x); o.y = f2bf_rne(v.y);
            o.z = f2bf_rne(v.z); o.w = f2bf_rne(v.w);
        } else {
            o.x = 0; o.y = 0; o.z = 0; o.w = 0;
        }
        out[i] = o;
    }
}

// ---- main GEMM + per-tile online-LSE epilogue ------------------------------
// 1D grid of 18992 blocks; XCD-bijective remap (18992 = 8 * 2374) so each
// XCD owns contiguous (nb, mb) ranges -> each 512KB weight slab hits one L2.
// block = 256 threads (4 waves 2x2).

__global__ __launch_bounds__(256, 4) void gemm_lse(
    const unsigned short* __restrict__ hbf,   // [2048][2048] bf16 bits
    const unsigned short* __restrict__ wbf,   // [151936][2048] bf16 bits
    float* __restrict__ pmax,                 // [1187][2048]
    float* __restrict__ psum) {               // [1187][2048]
    __shared__ short ldsA[BM * BK];   // [128 rows][8 chunks of 16B], XOR-swizzled
    __shared__ short ldsB[BN * BK];
    __shared__ float eM[BM][2];
    __shared__ float eS[BM][2];

    const int t    = threadIdx.x;
    const int lane = t & 63;
    const int w    = t >> 6;
    const int wm   = w >> 1;          // wave row (0..1) -> 64 rows
    const int wn   = w & 1;           // wave col (0..1) -> 64 cols

    // XCD-aware bijective remap: hw block b -> xcd = b&7 (round-robin
    // dispatch), give each XCD a contiguous linear range.
    const int b    = blockIdx.x;
    const int lin  = (b & 7) * (NBLK / 8) + (b >> 3);
    const int mb   = lin & 15;        // m-block fast -> 16 blocks share W slab
    const int nb   = lin >> 4;
    const int m0   = mb * BM;
    const int n0   = nb * BN;

    // Staging: thread t fills physical LDS row srow=t>>3 (+32/issue),
    // physical 16B-chunk (t&7). T2 swizzle: physical chunk c holds logical
    // chunk c ^ (row&7)  -> pre-swizzle the GLOBAL source (rule 21).
    const int srow   = t >> 3;
    const int schunk = (t & 7) ^ (srow & 7);   // (srow+32i)&7 == srow&7
    const unsigned short* pa = hbf + (size_t)(m0 + srow) * H_SIZE + schunk * 8;
    const unsigned short* pb = wbf + (size_t)(n0 + srow) * H_SIZE + schunk * 8;
    short* la = &ldsA[t * 8];
    short* lb = &ldsB[t * 8];

    floatx4 zero4 = {0.f, 0.f, 0.f, 0.f};
    floatx4 acc[4][4];
#pragma unroll
    for (int i = 0; i < 4; ++i)
#pragma unroll
        for (int j = 0; j < 4; ++j) acc[i][j] = zero4;

    const int fr  = lane & 15;      // fragment row/col within 16x16
    const int fq  = lane >> 4;      // k-subchunk selector (0..3)
    const int rsw = fr & 7;         // read-side swizzle term: row&7 == fr&7

    for (int kt = 0; kt < H_SIZE / BK; ++kt) {
        const int kof = kt * BK;
#pragma unroll
        for (int i = 0; i < 4; ++i) {
            gload16(pa + (size_t)i * 32 * H_SIZE + kof, la + i * 2048);
            gload16(pb + (size_t)i * 32 * H_SIZE + kof, lb + i * 2048);
        }
        __syncthreads();
#pragma unroll
        for (int kk = 0; kk < 2; ++kk) {
            bf16x8 af[4], bfv[4];
#pragma unroll
            for (int i = 0; i < 4; ++i)
                af[i] = *(const bf16x8*)&ldsA[(wm * 64 + i * 16 + fr) * BK
                                              + (((kk * 4 + fq) ^ rsw) * 8)];
#pragma unroll
            for (int j = 0; j < 4; ++j)
                bfv[j] = *(const bf16x8*)&ldsB[(wn * 64 + j * 16 + fr) * BK
                                               + (((kk * 4 + fq) ^ rsw) * 8)];
#pragma unroll
            for (int i = 0; i < 4; ++i)
#pragma unroll
                for (int j = 0; j < 4; ++j)
                    acc[i][j] = __builtin_amdgcn_mfma_f32_16x16x32_bf16(
                        af[i], bfv[j], acc[i][j], 0, 0, 0);
        }
        __syncthreads();
    }

    // epilogue: per-row max + sum(exp) over this block's 128 vocab columns.
    // C/D layout: col = lane&15, row = (lane>>4)*4 + reg.
#pragma unroll
    for (int i = 0; i < 4; ++i) {
#pragma unroll
        for (int r = 0; r < 4; ++r) {
            float v = -INFINITY;
#pragma unroll
            for (int j = 0; j < 4; ++j) v = fmaxf(v, acc[i][j][r]);
            for (int off = 1; off < 16; off <<= 1)
                v = fmaxf(v, __shfl_xor(v, off, 64));
            float s = 0.f;
#pragma unroll
            for (int j = 0; j < 4; ++j) s += expf(acc[i][j][r] - v);
            for (int off = 1; off < 16; off <<= 1)
                s += __shfl_xor(s, off, 64);
            if (fr == 0) {
                int row = wm * 64 + i * 16 + fq * 4 + r;
                eM[row][wn] = v;
                eS[row][wn] = s;
            }
        }
    }
    __syncthreads();
    if (t < BM) {
        float ma = eM[t][0], mb2 = eM[t][1];
        float Mx = fmaxf(ma, mb2);
        float Sx = eS[t][0] * expf(ma - Mx) + eS[t][1] * expf(mb2 - Mx);
        size_t grow = (size_t)m0 + t;
        pmax[(size_t)nb * M_ROWS + grow] = Mx;
        psum[(size_t)nb * M_ROWS + grow] = Sx;
    }
}

// ---- per-row reduction: combine partials + exact fp32 target dot -----------

__global__ void zero_acc(float* a) {
    if (threadIdx.x < 2) a[threadIdx.x] = 0.f;
}

__global__ __launch_bounds__(256) void reduce_rows(
    const float* __restrict__ hid,      // original fp32 hidden (row m = shift row m)
    const int* __restrict__ labels,     // int32 labels, length 2048
    const float* __restrict__ wt,       // fp32 weight
    const float* __restrict__ pmax,
    const float* __restrict__ psum,
    float* __restrict__ accum) {
    const int m = blockIdx.x;           // 0..2046
    const int t = threadIdx.x;
    const int lbl = labels[m + 1];
    const bool valid = (lbl != IGNORE_INDEX);

    float dot = 0.f;
    if (valid) {
        int li = lbl < 0 ? 0 : lbl;
        const float4* hr = (const float4*)(hid + (size_t)m * H_SIZE);
        const float4* wr = (const float4*)(wt + (size_t)li * H_SIZE);
#pragma unroll
        for (int i = 0; i < 2; ++i) {
            float4 a = hr[t + i * 256];
            float4 b = wr[t + i * 256];
            dot += a.x * b.x + a.y * b.y + a.z * b.z + a.w * b.w;
        }
    }

    float M = -INFINITY, S = 0.f;
    for (int nbi = t; nbi < NB_CNT; nbi += 256) {
        float m2 = pmax[(size_t)nbi * M_ROWS + m];
        float s2 = psum[(size_t)nbi * M_ROWS + m];
        if (m2 > M) { S = S * expf(M - m2) + s2; M = m2; }
        else        { S += s2 * expf(m2 - M); }
    }
    // butterfly over 64-lane wave
    for (int off = 1; off < 64; off <<= 1) {
        float M2 = __shfl_xor(M, off, 64);
        float S2 = __shfl_xor(S, off, 64);
        float nm = fmaxf(M, M2);
        S = S * expf(M - nm) + S2 * expf(M2 - nm);
        M = nm;
        dot += __shfl_xor(dot, off, 64);
    }
    __shared__ float rM[4], rS[4], rD[4];
    const int wv = t >> 6, lane = t & 63;
    if (lane == 0) { rM[wv] = M; rS[wv] = S; rD[wv] = dot; }
    __syncthreads();
    if (t == 0) {
        float Mx = rM[0], Sx = rS[0], D = rD[0];
        for (int i = 1; i < 4; ++i) {
            float nm = fmaxf(Mx, rM[i]);
            Sx = Sx * expf(Mx - nm) + rS[i] * expf(rM[i] - nm);
            Mx = nm;
            D += rD[i];
        }
        if (valid) {
            atomicAdd(&accum[0], (Mx + logf(Sx)) - D);
            atomicAdd(&accum[1], 1.0f);
        }
    }
}

__global__ void finalize(const float* __restrict__ accum, float* __restrict__ out) {
    out[0] = accum[0] / accum[1];
}

__global__ void sentinel(float* out) { out[0] = -12345.0f; }

// ---------------------------------------------------------------------------

extern "C" void kernel_launch(void* const* d_in, const int* in_sizes, int n_in,
                              void* d_out, int out_size, void* d_ws, size_t ws_size,
                              hipStream_t stream) {
    const float* hid    = (const float*)d_in[0];
    const int*   labels = (const int*)d_in[1];
    const float* wt     = (const float*)d_in[2];
    float* out = (float*)d_out;

    const size_t wbf_bytes  = (size_t)V_SIZE * H_SIZE * 2;     // 622,333,952
    const size_t hbf_bytes  = (size_t)M_ROWS * H_SIZE * 2;     //   8,388,608
    const size_t part_bytes = (size_t)NB_CNT * M_ROWS * 4;     //   9,723,904
    const size_t off_wbf  = 0;
    const size_t off_hbf  = off_wbf + wbf_bytes;
    const size_t off_pmax = off_hbf + hbf_bytes;
    const size_t off_psum = off_pmax + part_bytes;
    const size_t off_acc  = off_psum + part_bytes;
    const size_t need     = off_acc + 16;

    if (ws_size < need) {   // diagnosable failure: out = -12345
        sentinel<<<1, 1, 0, stream>>>(out);
        return;
    }

    unsigned short* wbf = (unsigned short*)((char*)d_ws + off_wbf);
    unsigned short* hbf = (unsigned short*)((char*)d_ws + off_hbf);
    float* pmax = (float*)((char*)d_ws + off_pmax);
    float* psum = (float*)((char*)d_ws + off_psum);
    float* accum = (float*)((char*)d_ws + off_acc);

    zero_acc<<<1, 64, 0, stream>>>(accum);

    long w4 = (long)V_SIZE * H_SIZE / 4;
    cvt_weight<<<2048, 256, 0, stream>>>((const float4*)wt, (ushort4*)wbf, w4);
    cvt_hidden<<<1024, 256, 0, stream>>>((const float4*)hid, (ushort4*)hbf);

    gemm_lse<<<NBLK, 256, 0, stream>>>(hbf, wbf, pmax, psum);

    reduce_rows<<<M_REAL, 256, 0, stream>>>(hid, labels, wt, pmax, psum, accum);
    finalize<<<1, 1, 0, stream>>>(accum, out);
}